// Round 8
// baseline (493.284 us; speedup 1.0000x reference)
//
#include <hip/hip_runtime.h>
#include <math.h>

#define D_MODEL 300
#define LSEQ    512
#define NBATCH  300
#define VOCAB   32000
#define NENT    (NBATCH * LSEQ)     // 153600 (i,l) entries
#define KCH2    50                  // scatter e-slice width (300 = 6*50)
#define ECH2    6                   // scatter e-chunks
#define NGRP    10                  // entry groups per scatter block (10*50 = 500 thr)
#define NBLK    64                  // entry-chunk splits for scatter
#define EPB     (NENT / NBLK)       // 2400 entries per scatter block
#define EPG     (EPB / NGRP)        // 240 entries per group
#define ACCSZ   (NBATCH * KCH2)     // 15000 floats = 60 KB LDS acc
#define FKCH    75                  // fc1 k-chunk
#define FECH    4                   // fc1 k-splits
#define TI      6                   // i-rows per termB block
#define JPB     2                   // j-rows per fc1 block
#define SCALE   17.32050807568877f  // sqrt(300)
#define C2      0.030701134573253947f  // ln(10000)/300
#define PIH     1.5707963267948966f

// ---- pass 1: histogram of x1 values ----
__global__ void count_kernel(const int* __restrict__ x1, int* __restrict__ cnt) {
    int idx = blockIdx.x * 256 + threadIdx.x;
    if (idx < NENT) atomicAdd(&cnt[x1[idx]], 1);
}

// ---- pass 2: exclusive scan over 32000 bins (single block, 1024 thr, 32 bins/thr) ----
__global__ __launch_bounds__(1024) void scan_kernel(const int* __restrict__ cnt,
                                                    int* __restrict__ cur) {
    __shared__ int lds[1024];
    const int t = threadIdx.x;
    const int v0 = t * 32;
    int local[32];
    int tot = 0;
    #pragma unroll
    for (int k = 0; k < 32; ++k) {
        int v = v0 + k;
        int c = (v < VOCAB) ? cnt[v] : 0;
        local[k] = tot;           // exclusive within thread
        tot += c;
    }
    lds[t] = tot;
    __syncthreads();
    int mysum = tot;
    for (int d = 1; d < 1024; d <<= 1) {
        int add = (t >= d) ? lds[t - d] : 0;
        __syncthreads();
        lds[t] += add;
        __syncthreads();
    }
    int base = lds[t] - mysum;    // exclusive across threads
    #pragma unroll
    for (int k = 0; k < 32; ++k) {
        int v = v0 + k;
        if (v < VOCAB) cur[v] = base + local[k];
    }
}

// ---- pass 3: scatter entries into v-sorted order; entry = (v<<9|i, SCALE*S) ----
__global__ void fill_kernel(const int* __restrict__ x1, const int* __restrict__ x2,
                            const float* __restrict__ emb2, int* __restrict__ cur,
                            int2* __restrict__ entries) {
    int idx = blockIdx.x * 256 + threadIdx.x;
    if (idx >= NENT) return;
    int i = idx >> 9, l = idx & (LSEQ - 1);
    int v = x1[idx];
    float dvi = __expf(-C2 * (float)(i & ~1));
    float arg = (float)l * dvi + ((i & 1) ? PIH : 0.0f);
    float S = fmaf(emb2[(size_t)x2[idx] * D_MODEL + i], SCALE, __sinf(arg));
    int pos = atomicAdd(&cur[v], 1);
    entries[pos] = make_int2((v << 9) | i, __float_as_int(SCALE * S));
}

// ---- term A scatter v2: v-sorted entries, emb1 streamed.
// 60 KB LDS acc (2 blocks/CU), 10 groups x 50 lanes, 8-deep register-prefetch
// pipeline (entry batch m+1 issued before batch m's atomics retire).
__global__ __launch_bounds__(512, 4) void scatter_kernel(const float* __restrict__ emb1,
                                                         const int2* __restrict__ entries,
                                                         float* __restrict__ P) {
    __shared__ float acc[ACCSZ];          // 300 i x 50 e = 60 KB
    const int tid = threadIdx.x;
    const int bx  = blockIdx.x;           // entry chunk
    const int ec  = blockIdx.y;           // e chunk
    const int e0  = ec * KCH2;

    for (int p = tid; p < ACCSZ; p += 512) acc[p] = 0.0f;
    __syncthreads();

    if (tid < NGRP * KCH2) {
        const int g    = tid / KCH2;
        const int lane = tid - g * KCH2;
        const float* e1l = emb1 + e0 + lane;
        const int base = bx * EPB + g;    // interleaved: groups share v-locality

        int2 e[8];
        #pragma unroll
        for (int k = 0; k < 8; ++k) e[k] = entries[base + NGRP * k];

        for (int m = 0; m < EPG; m += 8) {
            // 8 independent row-slice loads (sorted v -> L2 hits / streaming)
            float r[8];
            #pragma unroll
            for (int k = 0; k < 8; ++k)
                r[k] = e1l[(size_t)(e[k].x >> 9) * D_MODEL];
            // prefetch next entry batch while rows are in flight
            int2 en[8];
            #pragma unroll
            for (int k = 0; k < 8; ++k) {
                int src = base + NGRP * (m + 8 + k);
                en[k] = entries[src < NENT ? src : 0];   // tail guard (values unused)
            }
            // accumulate
            #pragma unroll
            for (int k = 0; k < 8; ++k)
                atomicAdd(&acc[(e[k].x & 511) * KCH2 + lane],
                          __int_as_float(e[k].y) * r[k]);
            #pragma unroll
            for (int k = 0; k < 8; ++k) e[k] = en[k];
        }
    }
    __syncthreads();

    float* myP = P + (size_t)(ec * NBLK + bx) * ACCSZ;
    for (int p = tid; p < ACCSZ; p += 512) myP[p] = acc[p];
}

// ---- reduce partials: Dm[i][ec*50+c] = sum_b P[ec][b][i][c]  (plain stores) ----
__global__ void reduce_kernel(const float* __restrict__ P, float* __restrict__ Dm) {
    const int p  = blockIdx.x * 256 + threadIdx.x;
    const int ec = blockIdx.y;
    if (p >= ACCSZ) return;
    float s = 0.0f;
    #pragma unroll 8
    for (int b = 0; b < NBLK; ++b)
        s += P[(size_t)(ec * NBLK + b) * ACCSZ + p];
    const int i = p / KCH2, c = p - i * KCH2;
    Dm[i * D_MODEL + ec * KCH2 + c] = s;
}

// ---- term B: Dm[i][e] += sum_l S[i,l] * pe[l][e]; pe in-register ----
__global__ void termB_kernel(const int* __restrict__ x2, const float* __restrict__ emb2,
                             float* __restrict__ Dm) {
    __shared__ float sS[TI][64];
    const int i0  = blockIdx.x * TI;
    const int l0  = blockIdx.y * 64;
    const int tid = threadIdx.x;

    for (int t = tid; t < TI * 64; t += 320) {
        const int ti = t >> 6, lr = t & 63;
        const int gi = i0 + ti, gl = l0 + lr;
        const float dvi = __expf(-C2 * (float)(gi & ~1));
        const float arg = (float)gl * dvi + ((gi & 1) ? PIH : 0.0f);
        sS[ti][lr] = fmaf(emb2[(size_t)x2[gi * LSEQ + gl] * D_MODEL + gi], SCALE, __sinf(arg));
    }
    __syncthreads();

    if (tid < D_MODEL) {
        const float dv = __expf(-C2 * (float)(tid & ~1));
        const float ph = (tid & 1) ? PIH : 0.0f;
        float a0 = 0.f, a1 = 0.f, a2 = 0.f, a3 = 0.f, a4 = 0.f, a5 = 0.f;
        #pragma unroll 8
        for (int l = 0; l < 64; ++l) {
            const float pv = __sinf((float)(l0 + l) * dv + ph);
            a0 = fmaf(sS[0][l], pv, a0);
            a1 = fmaf(sS[1][l], pv, a1);
            a2 = fmaf(sS[2][l], pv, a2);
            a3 = fmaf(sS[3][l], pv, a3);
            a4 = fmaf(sS[4][l], pv, a4);
            a5 = fmaf(sS[5][l], pv, a5);
        }
        atomicAdd(&Dm[(i0 + 0) * D_MODEL + tid], a0);
        atomicAdd(&Dm[(i0 + 1) * D_MODEL + tid], a1);
        atomicAdd(&Dm[(i0 + 2) * D_MODEL + tid], a2);
        atomicAdd(&Dm[(i0 + 3) * D_MODEL + tid], a3);
        atomicAdd(&Dm[(i0 + 4) * D_MODEL + tid], a4);
        atomicAdd(&Dm[(i0 + 5) * D_MODEL + tid], a5);
    }
}

// fc1 k-split partial: Hpre[j][e] += sum_{k in chunk} w1[j,k]*Dm[k][e]
__global__ void fc1_kernel(const float* __restrict__ w1, const float* __restrict__ Dm,
                           float* __restrict__ Hpre) {
    const int j0  = blockIdx.x * JPB;
    const int sp  = blockIdx.y;
    const int tid = threadIdx.x;
    const int k0  = sp * FKCH;
    if (tid >= D_MODEL) return;
    const float* w1r0 = w1 + (j0 + 0) * D_MODEL + k0;
    const float* w1r1 = w1 + (j0 + 1) * D_MODEL + k0;
    float acc0 = 0.0f, acc1 = 0.0f;
    #pragma unroll 5
    for (int k = 0; k < FKCH; ++k) {
        float d = Dm[(k0 + k) * D_MODEL + tid];
        acc0 = fmaf(w1r0[k], d, acc0);
        acc1 = fmaf(w1r1[k], d, acc1);
    }
    atomicAdd(&Hpre[(j0 + 0) * D_MODEL + tid], acc0);
    atomicAdd(&Hpre[(j0 + 1) * D_MODEL + tid], acc1);
}

// Fused bias + relu + fc2 + softmax. Block = 256 = 64 e-lanes x 4 j-chunks.
__global__ void fc2_softmax_kernel(const float* __restrict__ Hpre, const float* __restrict__ b1,
                                   const float* __restrict__ w2, const float* __restrict__ b2,
                                   float* __restrict__ out) {
    __shared__ float sm[4][4][64];
    const int tid   = threadIdx.x;
    const int e_loc = tid & 63;
    const int jc    = tid >> 6;
    const int e     = blockIdx.x * 64 + e_loc;

    float a0 = 0.f, a1 = 0.f, a2 = 0.f, a3 = 0.f;
    if (e < D_MODEL) {
        const int j0 = jc * 75;
        #pragma unroll 5
        for (int j = j0; j < j0 + 75; ++j) {
            float h = fmaxf(Hpre[j * D_MODEL + e] + b1[j], 0.0f);
            a0 = fmaf(h, w2[0 * D_MODEL + j], a0);
            a1 = fmaf(h, w2[1 * D_MODEL + j], a1);
            a2 = fmaf(h, w2[2 * D_MODEL + j], a2);
            a3 = fmaf(h, w2[3 * D_MODEL + j], a3);
        }
    }
    sm[jc][0][e_loc] = a0; sm[jc][1][e_loc] = a1;
    sm[jc][2][e_loc] = a2; sm[jc][3][e_loc] = a3;
    __syncthreads();

    if (jc == 0 && e < D_MODEL) {
        float l0 = b2[0] + sm[0][0][e_loc] + sm[1][0][e_loc] + sm[2][0][e_loc] + sm[3][0][e_loc];
        float l1 = b2[1] + sm[0][1][e_loc] + sm[1][1][e_loc] + sm[2][1][e_loc] + sm[3][1][e_loc];
        float l2 = b2[2] + sm[0][2][e_loc] + sm[1][2][e_loc] + sm[2][2][e_loc] + sm[3][2][e_loc];
        float l3 = b2[3] + sm[0][3][e_loc] + sm[1][3][e_loc] + sm[2][3][e_loc] + sm[3][3][e_loc];
        float m  = fmaxf(fmaxf(l0, l1), fmaxf(l2, l3));
        float x0 = expf(l0 - m), x1 = expf(l1 - m), x2 = expf(l2 - m), x3 = expf(l3 - m);
        float inv = 1.0f / (x0 + x1 + x2 + x3);
        out[e * 4 + 0] = x0 * inv;
        out[e * 4 + 1] = x1 * inv;
        out[e * 4 + 2] = x2 * inv;
        out[e * 4 + 3] = x3 * inv;
    }
}

extern "C" void kernel_launch(void* const* d_in, const int* in_sizes, int n_in,
                              void* d_out, int out_size, void* d_ws, size_t ws_size,
                              hipStream_t stream) {
    const int*   x1   = (const int*)d_in[0];
    const int*   x2   = (const int*)d_in[1];
    const float* emb1 = (const float*)d_in[2];
    const float* emb2 = (const float*)d_in[3];
    const float* w1   = (const float*)d_in[4];
    const float* b1   = (const float*)d_in[5];
    const float* w2   = (const float*)d_in[6];
    const float* b2   = (const float*)d_in[7];
    float* out = (float*)d_out;

    char* ws = (char*)d_ws;
    int*   cnt     = (int*)ws;                        // 32000*4  = 128000
    float* Hpre    = (float*)(ws + 128000);           // 90000*4  = 360000
    int*   cur     = (int*)(ws + 488000);             // 32000*4  = 128000
    int2*  entries = (int2*)(ws + 616000);            // 153600*8 = 1228800
    float* P       = (float*)(ws + 1844800);          // 384*15000*4 = 23040000
    float* Dm      = (float*)(ws + 24884800);         // 90000*4  = 360000

    // zero cnt + Hpre (contiguous)
    (void)hipMemsetAsync(ws, 0, 488000, stream);

    count_kernel<<<(NENT + 255) / 256, 256, 0, stream>>>(x1, cnt);
    scan_kernel<<<1, 1024, 0, stream>>>(cnt, cur);
    fill_kernel<<<(NENT + 255) / 256, 256, 0, stream>>>(x1, x2, emb2, cur, entries);
    scatter_kernel<<<dim3(NBLK, ECH2), 512, 0, stream>>>(emb1, entries, P);
    reduce_kernel<<<dim3((ACCSZ + 255) / 256, ECH2), 256, 0, stream>>>(P, Dm);
    termB_kernel<<<dim3(NBATCH / TI, LSEQ / 64), 320, 0, stream>>>(x2, emb2, Dm);
    fc1_kernel<<<dim3(D_MODEL / JPB, FECH), 320, 0, stream>>>(w1, Dm, Hpre);
    fc2_softmax_kernel<<<(D_MODEL + 63) / 64, 256, 0, stream>>>(Hpre, b1, w2, b2, out);
}

// Round 9
// 166.482 us; speedup vs baseline: 2.9630x; 2.9630x over previous
//
#include <hip/hip_runtime.h>
#include <math.h>

#define D_MODEL 300
#define LSEQ    512
#define NBATCH  300
#define SPLIT   16
#define LCH     (LSEQ / SPLIT)      // 32 l-values per diagAB block
#define NG      4                   // parallel l-streams per block
#define LPG     (LCH / NG)          // 8 l-values per stream
#define NR      75                  // float4 lanes per row (75*4 = 300)
#define KCH     (D_MODEL / 4)       // 75, fc1 k-chunk
#define JPB     2                   // j-rows per fc1 block
#define SCALE   17.32050807568877f  // sqrt(300)
#define C2      0.030701134573253947f  // ln(10000)/300
#define PIH     1.5707963267948966f    // pi/2

// Fused diag kernel: Dm[i][e] += sum_{l in chunk} S[l] * (SCALE*emb1[x1[i,l]][e] + pe[l][e])
//  - S[l] = emb2[x2[i,l]][i]*SCALE + pe[l][i], computed in staging (pe inline)
//  - term B first (pure VALU), then term A in 8 vocab-sliced temporal passes:
//    all blocks sweep slice p=0..7 (4096 rows = 4.9 MB ~ per-XCD L2), so row
//    re-references across blocks hit L2/L3 instead of re-fetching HBM.
__global__ void diagAB_kernel(const int* __restrict__ x1, const int* __restrict__ x2,
                              const float* __restrict__ emb1, const float* __restrict__ emb2,
                              float* __restrict__ Dm) {
    __shared__ int    x1ch[LCH];
    __shared__ float  sch[LCH];   // raw S values
    __shared__ float4 part[NG][NR];
    const int i   = blockIdx.x;   // batch index (== diagonal index)
    const int sp  = blockIdx.y;   // l-chunk
    const int tid = threadIdx.x;
    const int l0  = sp * LCH;

    if (tid < LCH) {
        const int l = l0 + tid;
        x1ch[tid] = x1[i * LSEQ + l];
        const int v2 = x2[i * LSEQ + l];
        const float dvi = __expf(-C2 * (float)(i & ~1));
        const float arg = (float)l * dvi + ((i & 1) ? PIH : 0.0f);
        sch[tid] = fmaf(emb2[(size_t)v2 * D_MODEL + i], SCALE, __sinf(arg));
    }
    __syncthreads();

    const int g = tid / NR;       // l-stream
    const int r = tid - g * NR;   // float4 index within row (e = 4r..4r+3)

    if (tid < NG * NR) {
        const int lb = g * LPG;   // this stream owns l0+lb .. l0+lb+7
        int   v[LPG];
        float s[LPG];
        #pragma unroll
        for (int k = 0; k < LPG; ++k) {
            v[k] = x1ch[lb + k];
            s[k] = sch[lb + k];
        }

        float ax = 0.f, ay = 0.f, az = 0.f, aw = 0.f;

        // ---- term B: pe in-register. e = 4r+{0,1,2,3} ----
        const float dvA = __expf(-C2 * (float)(4 * r));
        const float dvB = __expf(-C2 * (float)(4 * r + 2));
        #pragma unroll
        for (int q = 0; q < LPG; ++q) {
            const float fl = (float)(l0 + lb + q);
            const float aA = fl * dvA;
            const float aB = fl * dvB;
            ax = fmaf(s[q], __sinf(aA), ax);
            ay = fmaf(s[q], __cosf(aA), ay);
            az = fmaf(s[q], __sinf(aB), az);
            aw = fmaf(s[q], __cosf(aB), aw);
        }

        // ---- term A: 8 vocab-sliced passes (slice = v>>12, 4096 rows = 4.9 MB) ----
        #pragma unroll 1
        for (int p = 0; p < 8; ++p) {
            #pragma unroll
            for (int k = 0; k < LPG; ++k) {
                if ((v[k] >> 12) == p) {
                    const float4 vv = ((const float4*)(emb1 + (size_t)v[k] * D_MODEL))[r];
                    const float  t  = s[k] * SCALE;
                    ax = fmaf(t, vv.x, ax);
                    ay = fmaf(t, vv.y, ay);
                    az = fmaf(t, vv.z, az);
                    aw = fmaf(t, vv.w, aw);
                }
            }
        }
        part[g][r] = make_float4(ax, ay, az, aw);
    }
    __syncthreads();

    if (g == 0 && tid < NR) {
        float4 p0 = part[0][r], p1 = part[1][r], p2 = part[2][r], p3 = part[3][r];
        float* dst = Dm + i * D_MODEL + 4 * r;
        atomicAdd(dst + 0, p0.x + p1.x + p2.x + p3.x);
        atomicAdd(dst + 1, p0.y + p1.y + p2.y + p3.y);
        atomicAdd(dst + 2, p0.z + p1.z + p2.z + p3.z);
        atomicAdd(dst + 3, p0.w + p1.w + p2.w + p3.w);
    }
}

// fc1 k-split partial: Hpre[j][e] += sum_{k in chunk} w1[j,k]*Dm[k][e]
__global__ void fc1_kernel(const float* __restrict__ w1, const float* __restrict__ Dm,
                           float* __restrict__ Hpre) {
    const int j0  = blockIdx.x * JPB;
    const int sp  = blockIdx.y;
    const int tid = threadIdx.x;
    const int k0  = sp * KCH;
    if (tid >= D_MODEL) return;
    const float* w1r0 = w1 + (j0 + 0) * D_MODEL + k0;
    const float* w1r1 = w1 + (j0 + 1) * D_MODEL + k0;
    float acc0 = 0.0f, acc1 = 0.0f;
    #pragma unroll 5
    for (int k = 0; k < KCH; ++k) {
        float d = Dm[(k0 + k) * D_MODEL + tid];
        acc0 = fmaf(w1r0[k], d, acc0);
        acc1 = fmaf(w1r1[k], d, acc1);
    }
    atomicAdd(&Hpre[(j0 + 0) * D_MODEL + tid], acc0);
    atomicAdd(&Hpre[(j0 + 1) * D_MODEL + tid], acc1);
}

// Fused bias + relu + fc2 + softmax. Block = 256 thr = 64 e-lanes x 4 j-chunks.
__global__ void fc2_softmax_kernel(const float* __restrict__ Hpre, const float* __restrict__ b1,
                                   const float* __restrict__ w2, const float* __restrict__ b2,
                                   float* __restrict__ out) {
    __shared__ float sm[4][4][64];   // [jc][o][e_loc]
    const int tid   = threadIdx.x;
    const int e_loc = tid & 63;
    const int jc    = tid >> 6;
    const int e     = blockIdx.x * 64 + e_loc;

    float a0 = 0.f, a1 = 0.f, a2 = 0.f, a3 = 0.f;
    if (e < D_MODEL) {
        const int j0 = jc * 75;
        #pragma unroll 5
        for (int j = j0; j < j0 + 75; ++j) {
            float h = fmaxf(Hpre[j * D_MODEL + e] + b1[j], 0.0f);
            a0 = fmaf(h, w2[0 * D_MODEL + j], a0);
            a1 = fmaf(h, w2[1 * D_MODEL + j], a1);
            a2 = fmaf(h, w2[2 * D_MODEL + j], a2);
            a3 = fmaf(h, w2[3 * D_MODEL + j], a3);
        }
    }
    sm[jc][0][e_loc] = a0; sm[jc][1][e_loc] = a1;
    sm[jc][2][e_loc] = a2; sm[jc][3][e_loc] = a3;
    __syncthreads();

    if (jc == 0 && e < D_MODEL) {
        float l0 = b2[0] + sm[0][0][e_loc] + sm[1][0][e_loc] + sm[2][0][e_loc] + sm[3][0][e_loc];
        float l1 = b2[1] + sm[0][1][e_loc] + sm[1][1][e_loc] + sm[2][1][e_loc] + sm[3][1][e_loc];
        float l2 = b2[2] + sm[0][2][e_loc] + sm[1][2][e_loc] + sm[2][2][e_loc] + sm[3][2][e_loc];
        float l3 = b2[3] + sm[0][3][e_loc] + sm[1][3][e_loc] + sm[2][3][e_loc] + sm[3][3][e_loc];
        float m  = fmaxf(fmaxf(l0, l1), fmaxf(l2, l3));
        float x0 = expf(l0 - m), x1 = expf(l1 - m), x2 = expf(l2 - m), x3 = expf(l3 - m);
        float inv = 1.0f / (x0 + x1 + x2 + x3);
        out[e * 4 + 0] = x0 * inv;
        out[e * 4 + 1] = x1 * inv;
        out[e * 4 + 2] = x2 * inv;
        out[e * 4 + 3] = x3 * inv;
    }
}

extern "C" void kernel_launch(void* const* d_in, const int* in_sizes, int n_in,
                              void* d_out, int out_size, void* d_ws, size_t ws_size,
                              hipStream_t stream) {
    const int*   x1   = (const int*)d_in[0];
    const int*   x2   = (const int*)d_in[1];
    const float* emb1 = (const float*)d_in[2];
    const float* emb2 = (const float*)d_in[3];
    const float* w1   = (const float*)d_in[4];
    const float* b1   = (const float*)d_in[5];
    const float* w2   = (const float*)d_in[6];
    const float* b2   = (const float*)d_in[7];
    float* out = (float*)d_out;

    char* ws = (char*)d_ws;
    float* Dm   = (float*)ws;                  // 300*300*4 = 360000 B
    float* Hpre = (float*)(ws + 360000);       // 300*300*4 = 360000 B

    // zero both atomic-accumulated buffers (contiguous, 720 KB)
    (void)hipMemsetAsync(Dm, 0, 2 * 360000, stream);

    diagAB_kernel<<<dim3(NBATCH, SPLIT), 320, 0, stream>>>(x1, x2, emb1, emb2, Dm);
    fc1_kernel<<<dim3(D_MODEL / JPB, 4), 320, 0, stream>>>(w1, Dm, Hpre);
    fc2_softmax_kernel<<<(D_MODEL + 63) / 64, 256, 0, stream>>>(Hpre, b1, w2, b2, out);
}

// Round 10
// 154.898 us; speedup vs baseline: 3.1846x; 1.0748x over previous
//
#include <hip/hip_runtime.h>
#include <math.h>

#define D_MODEL 300
#define LSEQ    512
#define NBATCH  300
#define SPLIT   16
#define LCH     (LSEQ / SPLIT)      // 32 l-values per diagAB block
#define NG      4                   // parallel l-streams per block
#define LPG     (LCH / NG)          // 8 l-values per stream
#define NR      75                  // float4 lanes per row (75*4 = 300)
#define KCH     (D_MODEL / 4)       // 75, fc1 k-chunk
#define JPB     2                   // j-rows per fc1 block
#define SCALE   17.32050807568877f  // sqrt(300)
#define C2      0.030701134573253947f  // ln(10000)/300
#define PIH     1.5707963267948966f    // pi/2 (cos x = sin(x+pi/2))

// Fused diag kernel: Dm[i][e] += sum_{l in chunk} S[l] * (SCALE*emb1[x1[i,l]][e] + pe[l][e])
//  - S[l] = emb2[x2[i,l]][i]*SCALE + pe[l][i], computed in staging (pe inline)
//  - term A: 8 unrolled float4 gathers of emb1 rows (latency floor ~42 us; three
//    reuse-locality restructures (sort-scatter, vocab slicing) all failed to beat it)
//  - term B: pe computed in-register (2 expf + sin/cos per l) -> no pe table at all.
__global__ void diagAB_kernel(const int* __restrict__ x1, const int* __restrict__ x2,
                              const float* __restrict__ emb1, const float* __restrict__ emb2,
                              float* __restrict__ Dm) {
    __shared__ int    x1ch[LCH];
    __shared__ float  sch[LCH];   // raw S values
    __shared__ float4 part[NG][NR];
    const int i   = blockIdx.x;   // batch index (== diagonal index)
    const int sp  = blockIdx.y;   // l-chunk
    const int tid = threadIdx.x;
    const int l0  = sp * LCH;

    if (tid < LCH) {
        const int l = l0 + tid;
        x1ch[tid] = x1[i * LSEQ + l];
        const int v2 = x2[i * LSEQ + l];
        const float dvi = __expf(-C2 * (float)(i & ~1));
        const float arg = (float)l * dvi + ((i & 1) ? PIH : 0.0f);
        sch[tid] = fmaf(emb2[(size_t)v2 * D_MODEL + i], SCALE, __sinf(arg));
    }
    __syncthreads();

    const int g = tid / NR;       // l-stream
    const int r = tid - g * NR;   // float4 index within row (e = 4r..4r+3)

    if (tid < NG * NR) {
        const int lb = g * LPG;   // this stream owns l0+lb .. l0+lb+7
        // ---- term A: 8 independent row gathers ----
        const float4 v0 = ((const float4*)(emb1 + (size_t)x1ch[lb + 0] * D_MODEL))[r];
        const float4 v1 = ((const float4*)(emb1 + (size_t)x1ch[lb + 1] * D_MODEL))[r];
        const float4 v2 = ((const float4*)(emb1 + (size_t)x1ch[lb + 2] * D_MODEL))[r];
        const float4 v3 = ((const float4*)(emb1 + (size_t)x1ch[lb + 3] * D_MODEL))[r];
        const float4 v4 = ((const float4*)(emb1 + (size_t)x1ch[lb + 4] * D_MODEL))[r];
        const float4 v5 = ((const float4*)(emb1 + (size_t)x1ch[lb + 5] * D_MODEL))[r];
        const float4 v6 = ((const float4*)(emb1 + (size_t)x1ch[lb + 6] * D_MODEL))[r];
        const float4 v7 = ((const float4*)(emb1 + (size_t)x1ch[lb + 7] * D_MODEL))[r];
        const float s0 = sch[lb + 0], s1 = sch[lb + 1], s2 = sch[lb + 2], s3 = sch[lb + 3];
        const float s4 = sch[lb + 4], s5 = sch[lb + 5], s6 = sch[lb + 6], s7 = sch[lb + 7];
        const float t0 = s0 * SCALE, t1 = s1 * SCALE, t2 = s2 * SCALE, t3 = s3 * SCALE;
        const float t4 = s4 * SCALE, t5 = s5 * SCALE, t6 = s6 * SCALE, t7 = s7 * SCALE;
        float ax, ay, az, aw;
        ax = t0 * v0.x;            ay = t0 * v0.y;            az = t0 * v0.z;            aw = t0 * v0.w;
        ax = fmaf(t1, v1.x, ax);   ay = fmaf(t1, v1.y, ay);   az = fmaf(t1, v1.z, az);   aw = fmaf(t1, v1.w, aw);
        ax = fmaf(t2, v2.x, ax);   ay = fmaf(t2, v2.y, ay);   az = fmaf(t2, v2.z, az);   aw = fmaf(t2, v2.w, aw);
        ax = fmaf(t3, v3.x, ax);   ay = fmaf(t3, v3.y, ay);   az = fmaf(t3, v3.z, az);   aw = fmaf(t3, v3.w, aw);
        ax = fmaf(t4, v4.x, ax);   ay = fmaf(t4, v4.y, ay);   az = fmaf(t4, v4.z, az);   aw = fmaf(t4, v4.w, aw);
        ax = fmaf(t5, v5.x, ax);   ay = fmaf(t5, v5.y, ay);   az = fmaf(t5, v5.z, az);   aw = fmaf(t5, v5.w, aw);
        ax = fmaf(t6, v6.x, ax);   ay = fmaf(t6, v6.y, ay);   az = fmaf(t6, v6.z, az);   aw = fmaf(t6, v6.w, aw);
        ax = fmaf(t7, v7.x, ax);   ay = fmaf(t7, v7.y, ay);   az = fmaf(t7, v7.z, az);   aw = fmaf(t7, v7.w, aw);

        // ---- term B: pe in-register. e = 4r+{0,1,2,3}; (e&~1) = {4r,4r,4r+2,4r+2} ----
        const float dvA = __expf(-C2 * (float)(4 * r));
        const float dvB = __expf(-C2 * (float)(4 * r + 2));
        const float s8[LPG] = {s0, s1, s2, s3, s4, s5, s6, s7};
        #pragma unroll
        for (int q = 0; q < LPG; ++q) {
            const float fl = (float)(l0 + lb + q);
            const float aA = fl * dvA;
            const float aB = fl * dvB;
            ax = fmaf(s8[q], __sinf(aA), ax);
            ay = fmaf(s8[q], __cosf(aA), ay);
            az = fmaf(s8[q], __sinf(aB), az);
            aw = fmaf(s8[q], __cosf(aB), aw);
        }
        part[g][r] = make_float4(ax, ay, az, aw);
    }
    __syncthreads();

    if (g == 0 && tid < NR) {
        float4 p0 = part[0][r], p1 = part[1][r], p2 = part[2][r], p3 = part[3][r];
        float* dst = Dm + i * D_MODEL + 4 * r;
        atomicAdd(dst + 0, p0.x + p1.x + p2.x + p3.x);
        atomicAdd(dst + 1, p0.y + p1.y + p2.y + p3.y);
        atomicAdd(dst + 2, p0.z + p1.z + p2.z + p3.z);
        atomicAdd(dst + 3, p0.w + p1.w + p2.w + p3.w);
    }
}

// fc1 k-split partial (proven ~6 us form): Hpre[j][e] += sum_{k in chunk} w1[j,k]*Dm[k][e]
__global__ void fc1_kernel(const float* __restrict__ w1, const float* __restrict__ Dm,
                           float* __restrict__ Hpre) {
    const int j0  = blockIdx.x * JPB;
    const int sp  = blockIdx.y;
    const int tid = threadIdx.x;
    const int k0  = sp * KCH;
    if (tid >= D_MODEL) return;
    const float* w1r0 = w1 + (j0 + 0) * D_MODEL + k0;
    const float* w1r1 = w1 + (j0 + 1) * D_MODEL + k0;
    float acc0 = 0.0f, acc1 = 0.0f;
    #pragma unroll 5
    for (int k = 0; k < KCH; ++k) {
        float d = Dm[(k0 + k) * D_MODEL + tid];
        acc0 = fmaf(w1r0[k], d, acc0);
        acc1 = fmaf(w1r1[k], d, acc1);
    }
    atomicAdd(&Hpre[(j0 + 0) * D_MODEL + tid], acc0);
    atomicAdd(&Hpre[(j0 + 1) * D_MODEL + tid], acc1);
}

// Fused bias + relu + fc2 + softmax. Block = 256 thr = 64 e-lanes x 4 j-chunks.
__global__ void fc2_softmax_kernel(const float* __restrict__ Hpre, const float* __restrict__ b1,
                                   const float* __restrict__ w2, const float* __restrict__ b2,
                                   float* __restrict__ out) {
    __shared__ float sm[4][4][64];   // [jc][o][e_loc]
    const int tid   = threadIdx.x;
    const int e_loc = tid & 63;
    const int jc    = tid >> 6;
    const int e     = blockIdx.x * 64 + e_loc;

    float a0 = 0.f, a1 = 0.f, a2 = 0.f, a3 = 0.f;
    if (e < D_MODEL) {
        const int j0 = jc * 75;
        #pragma unroll 5
        for (int j = j0; j < j0 + 75; ++j) {
            float h = fmaxf(Hpre[j * D_MODEL + e] + b1[j], 0.0f);
            a0 = fmaf(h, w2[0 * D_MODEL + j], a0);
            a1 = fmaf(h, w2[1 * D_MODEL + j], a1);
            a2 = fmaf(h, w2[2 * D_MODEL + j], a2);
            a3 = fmaf(h, w2[3 * D_MODEL + j], a3);
        }
    }
    sm[jc][0][e_loc] = a0; sm[jc][1][e_loc] = a1;
    sm[jc][2][e_loc] = a2; sm[jc][3][e_loc] = a3;
    __syncthreads();

    if (jc == 0 && e < D_MODEL) {
        float l0 = b2[0] + sm[0][0][e_loc] + sm[1][0][e_loc] + sm[2][0][e_loc] + sm[3][0][e_loc];
        float l1 = b2[1] + sm[0][1][e_loc] + sm[1][1][e_loc] + sm[2][1][e_loc] + sm[3][1][e_loc];
        float l2 = b2[2] + sm[0][2][e_loc] + sm[1][2][e_loc] + sm[2][2][e_loc] + sm[3][2][e_loc];
        float l3 = b2[3] + sm[0][3][e_loc] + sm[1][3][e_loc] + sm[2][3][e_loc] + sm[3][3][e_loc];
        float m  = fmaxf(fmaxf(l0, l1), fmaxf(l2, l3));
        float x0 = expf(l0 - m), x1 = expf(l1 - m), x2 = expf(l2 - m), x3 = expf(l3 - m);
        float inv = 1.0f / (x0 + x1 + x2 + x3);
        out[e * 4 + 0] = x0 * inv;
        out[e * 4 + 1] = x1 * inv;
        out[e * 4 + 2] = x2 * inv;
        out[e * 4 + 3] = x3 * inv;
    }
}

extern "C" void kernel_launch(void* const* d_in, const int* in_sizes, int n_in,
                              void* d_out, int out_size, void* d_ws, size_t ws_size,
                              hipStream_t stream) {
    const int*   x1   = (const int*)d_in[0];
    const int*   x2   = (const int*)d_in[1];
    const float* emb1 = (const float*)d_in[2];
    const float* emb2 = (const float*)d_in[3];
    const float* w1   = (const float*)d_in[4];
    const float* b1   = (const float*)d_in[5];
    const float* w2   = (const float*)d_in[6];
    const float* b2   = (const float*)d_in[7];
    float* out = (float*)d_out;

    char* ws = (char*)d_ws;
    float* Dm   = (float*)ws;                  // 300*300*4 = 360000 B
    float* Hpre = (float*)(ws + 360000);       // 300*300*4 = 360000 B

    // zero both atomic-accumulated buffers (contiguous, 720 KB ~ 0.1 us)
    (void)hipMemsetAsync(Dm, 0, 2 * 360000, stream);

    diagAB_kernel<<<dim3(NBATCH, SPLIT), 320, 0, stream>>>(x1, x2, emb1, emb2, Dm);
    fc1_kernel<<<dim3(D_MODEL / JPB, 4), 320, 0, stream>>>(w1, Dm, Hpre);
    fc2_softmax_kernel<<<(D_MODEL + 63) / 64, 256, 0, stream>>>(Hpre, b1, w2, b2, out);
}